// Round 1
// baseline (286.793 us; speedup 1.0000x reference)
//
#include <hip/hip_runtime.h>
#include <math.h>

constexpr int E_TOTAL = 320000;
constexpr int NODE_D  = 256;   // D
constexpr int K2      = 512;   // 2D
constexpr int H       = 64;

constexpr int BM     = 256;    // edges per block
constexpr int BK     = 32;     // K chunk
constexpr int NCHUNK = K2 / BK;  // 16

__device__ __forceinline__ float concrete_gate(float la, float u) {
    // sigmoid((la + log(u) - log1p(-u)) / 0.1)
    float z = (la + logf(u) - log1pf(-u)) * 10.0f;
    return 1.0f / (1.0f + expf(-z));
}

// ---------------- weight gates: wg1 (512x512) at out+320000, wg2 (512x256) at out+582144
__global__ void wgate_kernel(const float* __restrict__ wla1,
                             const float* __restrict__ wla2,
                             const float* __restrict__ u1,
                             const float* __restrict__ u2,
                             float* __restrict__ out)
{
    int tid = blockIdx.x * blockDim.x + threadIdx.x;  // 0..98303 (float4 granularity)
    const float4* la4;
    const float4* u4;
    float4* o4;
    int idx;
    if (tid < 65536) {                 // wg1: 262144 floats = 65536 float4
        la4 = (const float4*)wla1;
        u4  = (const float4*)u1;
        o4  = (float4*)(out + 320000);
        idx = tid;
    } else {                           // wg2: 131072 floats = 32768 float4
        la4 = (const float4*)wla2;
        u4  = (const float4*)u2;
        o4  = (float4*)(out + 582144);
        idx = tid - 65536;
    }
    float4 la = la4[idx];
    float4 u  = u4[idx];
    float4 r;
    r.x = concrete_gate(la.x, u.x);
    r.y = concrete_gate(la.y, u.y);
    r.z = concrete_gate(la.z, u.z);
    r.w = concrete_gate(la.w, u.w);
    o4[idx] = r;
}

// ---------------- edge MLP: out[e] = (relu(feat@W1+b1)@W2 + b2) * gate(la[e],u[e])
__global__ __launch_bounds__(256, 2)
void edge_mlp_kernel(const float* __restrict__ x,
                     const int*   __restrict__ eidx,
                     const float* __restrict__ la,
                     const float* __restrict__ W1,
                     const float* __restrict__ b1,
                     const float* __restrict__ W2,
                     const float* __restrict__ b2,
                     const float* __restrict__ u_edge,
                     float* __restrict__ out)
{
    __shared__ float sAt[BK][BM + 4];   // K-major A tile (feat^T), pad keeps 16B align + bank spread
    __shared__ float sW[BK][H];         // W1 chunk, row-major

    const int t  = threadIdx.x;
    const int e0 = blockIdx.x * BM;
    const int tr = t >> 3;     // 0..31 -> rows 8*tr .. 8*tr+7
    const int tc = t & 7;      // 0..7  -> cols 8*tc .. 8*tc+7

    // staging: this thread owns edge e0+t's feature row
    const int e_st = e0 + t;
    const int i_idx = eidx[e_st];
    const int j_idx = eidx[E_TOTAL + e_st];
    const float* xrow_i = x + (size_t)i_idx * NODE_D;
    const float* xrow_j = x + (size_t)j_idx * NODE_D;

    // W staging: thread t loads W1 row (k0 + t>>3), cols (t&7)*8 .. +7
    const int wrow = t >> 3;
    const int wcol = (t & 7) * 8;

    float4 ar[8];   // 32 floats of my edge row for next chunk
    float4 wr[2];   // 8 floats of W1 for next chunk

    auto load_chunk = [&](int kc) {
        const int k0 = kc * BK;
        const float* src = (k0 < NODE_D) ? (xrow_i + k0) : (xrow_j + (k0 - NODE_D));
        #pragma unroll
        for (int q = 0; q < 8; ++q)
            ar[q] = *reinterpret_cast<const float4*>(src + 4 * q);
        const float* wsrc = W1 + (size_t)(k0 + wrow) * H + wcol;
        wr[0] = *reinterpret_cast<const float4*>(wsrc);
        wr[1] = *reinterpret_cast<const float4*>(wsrc + 4);
    };

    auto store_chunk = [&]() {
        #pragma unroll
        for (int q = 0; q < 8; ++q) {
            sAt[4*q + 0][t] = ar[q].x;
            sAt[4*q + 1][t] = ar[q].y;
            sAt[4*q + 2][t] = ar[q].z;
            sAt[4*q + 3][t] = ar[q].w;
        }
        *reinterpret_cast<float4*>(&sW[wrow][wcol])     = wr[0];
        *reinterpret_cast<float4*>(&sW[wrow][wcol + 4]) = wr[1];
    };

    float acc[8][8];
    #pragma unroll
    for (int p = 0; p < 8; ++p)
        #pragma unroll
        for (int q = 0; q < 8; ++q)
            acc[p][q] = 0.0f;

    load_chunk(0);
    for (int kc = 0; kc < NCHUNK; ++kc) {
        __syncthreads();          // previous chunk's reads done
        store_chunk();
        __syncthreads();          // tile visible
        if (kc + 1 < NCHUNK) load_chunk(kc + 1);   // prefetch overlaps compute

        #pragma unroll 8
        for (int kk = 0; kk < BK; ++kk) {
            float4 a0 = *reinterpret_cast<const float4*>(&sAt[kk][8 * tr]);
            float4 a1 = *reinterpret_cast<const float4*>(&sAt[kk][8 * tr + 4]);
            float4 w0 = *reinterpret_cast<const float4*>(&sW[kk][8 * tc]);
            float4 w1v = *reinterpret_cast<const float4*>(&sW[kk][8 * tc + 4]);
            float av[8] = {a0.x, a0.y, a0.z, a0.w, a1.x, a1.y, a1.z, a1.w};
            float bv[8] = {w0.x, w0.y, w0.z, w0.w, w1v.x, w1v.y, w1v.z, w1v.w};
            #pragma unroll
            for (int p = 0; p < 8; ++p)
                #pragma unroll
                for (int q = 0; q < 8; ++q)
                    acc[p][q] = fmaf(av[p], bv[q], acc[p][q]);
        }
    }

    // epilogue: h = relu(acc + b1), sim = h @ W2 + b2, out = sim * gate
    float bb[8], ww[8];
    #pragma unroll
    for (int q = 0; q < 8; ++q) {
        bb[q] = b1[8 * tc + q];
        ww[q] = W2[8 * tc + q];
    }
    const float bias2 = b2[0];

    #pragma unroll
    for (int p = 0; p < 8; ++p) {
        float ps = 0.0f;
        #pragma unroll
        for (int q = 0; q < 8; ++q) {
            float h = acc[p][q] + bb[q];
            h = fmaxf(h, 0.0f);
            ps = fmaf(h, ww[q], ps);
        }
        // reduce across the 8 col-group lanes (tc = t&7, stays within wave)
        ps += __shfl_xor(ps, 1);
        ps += __shfl_xor(ps, 2);
        ps += __shfl_xor(ps, 4);
        if (tc == 0) {
            int e = e0 + 8 * tr + p;
            float sim = ps + bias2;
            out[e] = sim * concrete_gate(la[e], u_edge[e]);
        }
    }
}

extern "C" void kernel_launch(void* const* d_in, const int* in_sizes, int n_in,
                              void* d_out, int out_size, void* d_ws, size_t ws_size,
                              hipStream_t stream) {
    const float* x    = (const float*)d_in[0];
    const int*   ei   = (const int*)  d_in[1];
    const float* la   = (const float*)d_in[2];
    const float* W1   = (const float*)d_in[3];
    const float* b1   = (const float*)d_in[4];
    const float* W2   = (const float*)d_in[5];
    const float* b2   = (const float*)d_in[6];
    const float* wla1 = (const float*)d_in[7];
    const float* wla2 = (const float*)d_in[8];
    const float* ue   = (const float*)d_in[9];
    const float* u1   = (const float*)d_in[10];
    const float* u2   = (const float*)d_in[11];
    float* out = (float*)d_out;

    hipLaunchKernelGGL(wgate_kernel, dim3(384), dim3(256), 0, stream,
                       wla1, wla2, u1, u2, out);
    hipLaunchKernelGGL(edge_mlp_kernel, dim3(E_TOTAL / BM), dim3(256), 0, stream,
                       x, ei, la, W1, b1, W2, b2, ue, out);
}

// Round 2
// 80.999 us; speedup vs baseline: 3.5407x; 3.5407x over previous
//
#include <hip/hip_runtime.h>
#include <math.h>

typedef __attribute__((ext_vector_type(8))) short s8v;   // 8 bf16 (4 VGPRs)
typedef __attribute__((ext_vector_type(4))) float f4v;   // MFMA accumulator

constexpr int E_TOTAL = 320000;
constexpr int NODE_D  = 256;   // D
constexpr int K2      = 512;   // 2D
constexpr int H       = 64;

constexpr int BM  = 256;       // edges per block
constexpr int BK  = 64;        // K chunk (2 MFMA k-steps)
constexpr int NCH = K2 / BK;   // 8

// workspace layout (bytes)
constexpr unsigned XBF_ROWB = NODE_D * 2;            // 512 B per node row (bf16)
constexpr size_t   WT_OFF   = 10000ull * XBF_ROWB;   // 5,120,000 (16B aligned)

__device__ __forceinline__ unsigned short f2bf(float f) {
    unsigned u = __float_as_uint(f);
    u += 0x7fffu + ((u >> 16) & 1u);   // RNE
    return (unsigned short)(u >> 16);
}

__device__ __forceinline__ float concrete_gate(float la, float u) {
    float z = (la + logf(u) - log1pf(-u)) * 10.0f;
    return 1.0f / (1.0f + expf(-z));
}

#define GLDS16(gsrc, ldst) \
    __builtin_amdgcn_global_load_lds((const __attribute__((address_space(1))) unsigned int*)(gsrc), \
                                     (__attribute__((address_space(3))) unsigned int*)(ldst), 16, 0, 0)

// ---------------- prep: x (fp32) -> bf16 rows in ws
__global__ void conv_x_kernel(const float* __restrict__ x, unsigned short* __restrict__ xbf, int n8) {
    int tid = blockIdx.x * blockDim.x + threadIdx.x;
    if (tid >= n8) return;
    const float4* p = (const float4*)x + (size_t)tid * 2;
    float4 a = p[0], b = p[1];
    unsigned short r[8] = { f2bf(a.x), f2bf(a.y), f2bf(a.z), f2bf(a.w),
                            f2bf(b.x), f2bf(b.y), f2bf(b.z), f2bf(b.w) };
    *(uint4*)(xbf + (size_t)tid * 8) = *(const uint4*)r;
}

// ---------------- prep: W1 [512][64] fp32 -> W1^T [64][512] bf16 in ws
__global__ void conv_w_kernel(const float* __restrict__ W1, unsigned short* __restrict__ wt) {
    int tid = blockIdx.x * blockDim.x + threadIdx.x;   // 0..32767
    int k = tid >> 6, c = tid & 63;
    wt[c * 512 + k] = f2bf(W1[tid]);
}

// ---------------- weight gates: wg1 at out+320000, wg2 at out+582144
__global__ void wgate_kernel(const float* __restrict__ wla1,
                             const float* __restrict__ wla2,
                             const float* __restrict__ u1,
                             const float* __restrict__ u2,
                             float* __restrict__ out)
{
    int tid = blockIdx.x * blockDim.x + threadIdx.x;
    const float4* la4; const float4* u4; float4* o4; int idx;
    if (tid < 65536) { la4 = (const float4*)wla1; u4 = (const float4*)u1; o4 = (float4*)(out + 320000); idx = tid; }
    else             { la4 = (const float4*)wla2; u4 = (const float4*)u2; o4 = (float4*)(out + 582144); idx = tid - 65536; }
    float4 la = la4[idx], u = u4[idx], r;
    r.x = concrete_gate(la.x, u.x);
    r.y = concrete_gate(la.y, u.y);
    r.z = concrete_gate(la.z, u.z);
    r.w = concrete_gate(la.w, u.w);
    o4[idx] = r;
}

// ---------------- edge MLP via bf16 MFMA
// A = gathered feat rows [BM][K2] bf16, B = W1 [K2][H]; Wt = B^T stored [H][K2].
// LDS tiles row-major, 128 B rows, XOR-swizzled: LDS[row][byte b] holds element
// bytes (b ^ ((row&7)<<4)); written linear by global_load_lds with pre-swizzled
// global source (rule #21), read back with the same XOR.
__global__ __launch_bounds__(256, 2)
void edge_mlp_mfma(const unsigned short* __restrict__ xbf,   // [N][256] bf16
                   const unsigned short* __restrict__ wtbf,  // [64][512] bf16
                   const int*   __restrict__ eidx,
                   const float* __restrict__ la,
                   const float* __restrict__ b1,
                   const float* __restrict__ W2,
                   const float* __restrict__ b2,
                   const float* __restrict__ ue,
                   float* __restrict__ out)
{
    __shared__ unsigned short sA[2][BM][BK];  // 2 x 32 KB
    __shared__ unsigned short sB[2][H][BK];   // 2 x 8 KB   (total 80 KB -> 2 blocks/CU)

    const int t    = threadIdx.x;
    const int lane = t & 63;
    const int w    = t >> 6;          // wave 0..3, owns rows w*64..w*64+63
    const int e0   = blockIdx.x * BM;

    // ---- staging constants: lane covers row_rel = l>>3, bytes (l&7)*16 of a 128B row slice
    const int l8 = lane >> 3;                               // row within 8-row group
    const unsigned srcSwz = ((unsigned)(lane & 7) << 4) ^ ((unsigned)l8 << 4);

    // per-thread gathered-row byte offsets for its 8 A-staging slots
    unsigned offI[8], offJ[8];
    #pragma unroll
    for (int it = 0; it < 8; ++it) {
        int e = e0 + it * 32 + w * 8 + l8;
        offI[it] = (unsigned)eidx[e] * XBF_ROWB;
        offJ[it] = (unsigned)eidx[E_TOTAL + e] * XBF_ROWB;
    }

    const char* xb = (const char*)xbf;
    const char* wb = (const char*)wtbf;

    auto stageA = [&](int buf, int kc) {
        const bool left = kc < 4;
        const unsigned colb = (unsigned)(left ? kc : kc - 4) * 128u + srcSwz;
        #pragma unroll
        for (int it = 0; it < 8; ++it) {
            const char* src = xb + (left ? offI[it] : offJ[it]) + colb;
            unsigned short* dst = &sA[buf][it * 32 + w * 8][0];   // wave-uniform, lane writes +lane*16
            GLDS16(src, dst);
        }
    };
    auto stageB = [&](int buf, int kc) {
        #pragma unroll
        for (int it = 0; it < 2; ++it) {
            int c = it * 32 + w * 8 + l8;
            const char* src = wb + (unsigned)c * 1024u + (unsigned)kc * 128u + srcSwz;
            unsigned short* dst = &sB[buf][it * 32 + w * 8][0];
            GLDS16(src, dst);
        }
    };

    // ---- fragment-read constants
    const int cg = lane & 15;          // A row / B col within frag; also C col
    const int rg = lane >> 4;          // k-group 0..3; also C row group
    const unsigned rdSwz = ((unsigned)(lane & 7) << 4);
    const char* sAb = (const char*)&sA[0][0][0];
    const char* sBb = (const char*)&sB[0][0][0];
    const unsigned aRow = (unsigned)(w * 64 + cg) * 128u;
    const unsigned bRow = (unsigned)cg * 128u;

    f4v acc[4][4] = {};

    stageA(0, 0); stageB(0, 0);
    __syncthreads();                   // drains vmcnt(0): tile 0 resident

    int buf = 0;
    for (int kc = 0; kc < NCH; ++kc) {
        if (kc + 1 < NCH) { stageA(buf ^ 1, kc + 1); stageB(buf ^ 1, kc + 1); }  // prefetch overlaps compute
        const unsigned abase = (unsigned)buf * (BM * BK * 2);
        const unsigned bbase = (unsigned)buf * (H * BK * 2);
        #pragma unroll
        for (int ks = 0; ks < 2; ++ks) {
            const unsigned kb = (unsigned)(ks * 64 + rg * 16);
            s8v af[4], bfv[4];
            #pragma unroll
            for (int ar = 0; ar < 4; ++ar)
                af[ar] = *(const s8v*)(sAb + abase + aRow + (unsigned)ar * 2048u + (kb ^ rdSwz));
            #pragma unroll
            for (int bc = 0; bc < 4; ++bc)
                bfv[bc] = *(const s8v*)(sBb + bbase + bRow + (unsigned)bc * 2048u + (kb ^ rdSwz));
            #pragma unroll
            for (int ar = 0; ar < 4; ++ar)
                #pragma unroll
                for (int bc = 0; bc < 4; ++bc)
                    acc[ar][bc] = __builtin_amdgcn_mfma_f32_16x16x32_bf16(af[ar], bfv[bc], acc[ar][bc], 0, 0, 0);
        }
        __syncthreads();               // waits vmcnt(0): prefetch landed, all reads of buf done
        buf ^= 1;
    }

    // ---- epilogue: h = relu(acc + b1), sim = h @ W2 + b2, out = sim * gate
    // C/D layout: col = cg (global col bc*16+cg), row = rg*4 + reg (within 16-row frag ar)
    float b1v[4], w2v[4];
    #pragma unroll
    for (int bc = 0; bc < 4; ++bc) {
        b1v[bc] = b1[bc * 16 + cg];
        w2v[bc] = W2[bc * 16 + cg];
    }
    const float bias2 = b2[0];

    #pragma unroll
    for (int ar = 0; ar < 4; ++ar) {
        #pragma unroll
        for (int reg = 0; reg < 4; ++reg) {
            float s = 0.0f;
            #pragma unroll
            for (int bc = 0; bc < 4; ++bc) {
                float h = acc[ar][bc][reg] + b1v[bc];
                h = fmaxf(h, 0.0f);
                s = fmaf(h, w2v[bc], s);
            }
            // reduce over the 16 cols held by lanes sharing rg (masks 1,2,4,8 stay in-group)
            s += __shfl_xor(s, 1);
            s += __shfl_xor(s, 2);
            s += __shfl_xor(s, 4);
            s += __shfl_xor(s, 8);
            if (cg == 0) {
                int e = e0 + w * 64 + ar * 16 + rg * 4 + reg;
                out[e] = (s + bias2) * concrete_gate(la[e], ue[e]);
            }
        }
    }
}

extern "C" void kernel_launch(void* const* d_in, const int* in_sizes, int n_in,
                              void* d_out, int out_size, void* d_ws, size_t ws_size,
                              hipStream_t stream) {
    const float* x    = (const float*)d_in[0];
    const int*   ei   = (const int*)  d_in[1];
    const float* la   = (const float*)d_in[2];
    const float* W1   = (const float*)d_in[3];
    const float* b1   = (const float*)d_in[4];
    const float* W2   = (const float*)d_in[5];
    const float* b2   = (const float*)d_in[6];
    const float* wla1 = (const float*)d_in[7];
    const float* wla2 = (const float*)d_in[8];
    const float* ue   = (const float*)d_in[9];
    const float* u1   = (const float*)d_in[10];
    const float* u2   = (const float*)d_in[11];
    float* out = (float*)d_out;

    unsigned short* xbf = (unsigned short*)d_ws;
    unsigned short* wt  = (unsigned short*)((char*)d_ws + WT_OFF);

    const int n8 = in_sizes[0] / 8;    // 2,560,000 / 8 = 320,000

    hipLaunchKernelGGL(conv_x_kernel, dim3((n8 + 255) / 256), dim3(256), 0, stream, x, xbf, n8);
    hipLaunchKernelGGL(conv_w_kernel, dim3(128), dim3(256), 0, stream, W1, wt);
    hipLaunchKernelGGL(wgate_kernel, dim3(384), dim3(256), 0, stream, wla1, wla2, u1, u2, out);
    hipLaunchKernelGGL(edge_mlp_mfma, dim3(E_TOTAL / BM), dim3(256), 0, stream,
                       xbf, wt, ei, la, b1, W2, b2, ue, out);
}